// Round 11
// baseline (55.411 us; speedup 1.0000x reference)
//
#include <hip/hip_runtime.h>

// Element ids
#define E_EMPTY  0
#define E_WALL   1
#define E_SAND   2
#define E_WATER  3
#define E_GAS    4
#define E_WOOD   5
#define E_ICE    6
#define E_FIRE   7
#define E_PLANT  8
#define E_STONE  9
#define E_LAVA   10
#define E_ACID   11
#define E_DUST   12
#define E_CLONER 13

#define CH 18
#define HW (512*512)          // 2^18
#define NPIX (4*HW)
#define NWORLD (4*CH*HW)

typedef unsigned long long u64;
#define ONE8 0x0101010101010101ULL
#define K7F  0x7F7F7F7F7F7F7F7FULL
#define H80  0x8080808080808080ULL
#define LOWN 0x0F0F0F0F0F0F0F0FULL

__constant__ float c_dens[14] = {0.f,5.f,3.f,2.f,-1.f,5.f,5.f,0.f,5.f,4.f,3.f,2.f,3.f,5.f};
__constant__ float c_grav[14] = {1.f,0.f,1.f,1.f,1.f,0.f,1.f,1.f,0.f,1.f,1.f,1.f,1.f,0.f};

__device__ __forceinline__ u64 bcast(int k) { return ONE8 * (unsigned)k; }
// per-byte equality -> 0x01 bytes (requires bytes <= 0x7F)
__device__ __forceinline__ u64 eqb(u64 x, int k) {
  u64 y = x ^ bcast(k);
  return ((~(y + K7F)) >> 7) & ONE8;
}
// per-byte a >= b -> 0x01 bytes (requires bytes <= 0x7F)
__device__ __forceinline__ u64 geb(u64 a, u64 b) { return (((a | H80) - b) >> 7) & ONE8; }
// per-byte a > b
__device__ __forceinline__ u64 gtb(u64 a, u64 b) { return ONE8 ^ geb(b, a); }
// 0/1-byte mask -> 0x00/0xFF byte mask
__device__ __forceinline__ u64 mexp(u64 m) { return (m << 8) - m; }
__device__ __forceinline__ u64 fl01w(u64 e) { return eqb(e, E_FIRE) | eqb(e, E_LAVA); }
__device__ __forceinline__ u64 burn01w(u64 b) {
  u64 e = b & LOWN;
  return eqb(e,E_WOOD) | eqb(e,E_PLANT) | eqb(e,E_GAS) | eqb(e,E_DUST);
}
__device__ __forceinline__ u64 isblkw(u64 e) {
  return ONE8 ^ (eqb(e,E_EMPTY) | eqb(e,E_WALL) | eqb(e,E_ACID) | eqb(e,E_CLONER));
}

// ---- K1: decode one-hot world (9 planes) -> u8 id; fold all rand thresholds -> bit-pack.
// rb bits: 0: ri<0.05, 1: ri<0.2, 2: ri<0.3, 3: re<0.4, 4: rm>0.5, 5: dg<=0
__device__ __forceinline__ unsigned char decode1(float d, float g, float f, float wa,
                                                 float wo, float pl, float sa, float lv, float wt) {
  if (g < 0.5f) {
    if (wa > 0.5f) return E_WALL;
    if (wo > 0.5f) return E_WOOD;
    if (pl > 0.5f) return E_PLANT;
    return E_CLONER;
  }
  int di = (int)d;          // d in {-1,0,2,3,4,5}, exact
  if (di == 0) return (f > 0.5f) ? E_FIRE : E_EMPTY;
  if (di == 5) return E_ICE;
  if (di == 4) return E_STONE;
  if (di < 0)  return E_GAS;
  if (di == 3) { if (sa > 0.5f) return E_SAND; if (lv > 0.5f) return E_LAVA; return E_DUST; }
  return (wt > 0.5f) ? E_WATER : E_ACID;
}

__global__ __launch_bounds__(256) void k_prep(const float* __restrict__ w,
                                              const float* __restrict__ ri,
                                              const float* __restrict__ re,
                                              const float* __restrict__ rm,
                                              const float* __restrict__ dg,
                                              unsigned char* __restrict__ e0,
                                              unsigned char* __restrict__ rb) {
  int g = blockIdx.x * 256 + threadIdx.x;
  int base = g << 2;
  int b = base >> 18;
  int r = base & (HW - 1);
  const float* wb = w + (size_t)b * CH * HW + r;
  float4 D  = *reinterpret_cast<const float4*>(wb + (size_t)14 * HW);
  float4 G  = *reinterpret_cast<const float4*>(wb + (size_t)15 * HW);
  float4 F  = *reinterpret_cast<const float4*>(wb + (size_t)7  * HW);
  float4 WA = *reinterpret_cast<const float4*>(wb + (size_t)1  * HW);
  float4 WO = *reinterpret_cast<const float4*>(wb + (size_t)5  * HW);
  float4 PL = *reinterpret_cast<const float4*>(wb + (size_t)8  * HW);
  float4 SA = *reinterpret_cast<const float4*>(wb + (size_t)2  * HW);
  float4 LV = *reinterpret_cast<const float4*>(wb + (size_t)10 * HW);
  float4 WT = *reinterpret_cast<const float4*>(wb + (size_t)3  * HW);
  uchar4 e;
  e.x = decode1(D.x, G.x, F.x, WA.x, WO.x, PL.x, SA.x, LV.x, WT.x);
  e.y = decode1(D.y, G.y, F.y, WA.y, WO.y, PL.y, SA.y, LV.y, WT.y);
  e.z = decode1(D.z, G.z, F.z, WA.z, WO.z, PL.z, SA.z, LV.z, WT.z);
  e.w = decode1(D.w, G.w, F.w, WA.w, WO.w, PL.w, SA.w, LV.w, WT.w);
  *reinterpret_cast<uchar4*>(e0 + base) = e;

  float4 RI = *reinterpret_cast<const float4*>(ri + base);
  float4 RE = *reinterpret_cast<const float4*>(re + base);
  float4 RM = *reinterpret_cast<const float4*>(rm + base);
  float4 DG = *reinterpret_cast<const float4*>(dg + base);
  uchar4 q;
  q.x = (RI.x<0.05f?1:0)|(RI.x<0.2f?2:0)|(RI.x<0.3f?4:0)|(RE.x<0.4f?8:0)|(RM.x>0.5f?16:0)|(DG.x<=0.f?32:0);
  q.y = (RI.y<0.05f?1:0)|(RI.y<0.2f?2:0)|(RI.y<0.3f?4:0)|(RE.y<0.4f?8:0)|(RM.y>0.5f?16:0)|(DG.y<=0.f?32:0);
  q.z = (RI.z<0.05f?1:0)|(RI.z<0.2f?2:0)|(RI.z<0.3f?4:0)|(RE.z<0.4f?8:0)|(RM.z>0.5f?16:0)|(DG.z<=0.f?32:0);
  q.w = (RI.w<0.05f?1:0)|(RI.w<0.2f?2:0)|(RI.w<0.3f?4:0)|(RE.w<0.4f?8:0)|(RM.w>0.5f?16:0)|(DG.w<=0.f?32:0);
  *reinterpret_cast<uchar4*>(rb + base) = q;
}

// ---- SWAR fluid substep (verified exact in R8)
__device__ __forceinline__ void fstep(bool left, int el, u64& E, u64& D, u64& Gv, u64& mom,
                                      u64 rmB, u64 ndB, u64 ndW, u64 ndE,
                                      int laneL, int laneR) {
  u64 fd = geb(mom, bcast(33)) | (eqb(mom, 32) & rmB);
  int pkT = (int)(E >> 56) | (((int)(D >> 56)) << 8) | (((int)(Gv >> 56)) << 11)
          | (((int)(fd >> 56)) << 12);
  int pkB = ((int)E & 255) | (((int)D & 255) << 8) | (((int)Gv & 1) << 11)
          | (((int)fd & 1) << 12);
  int pL = __shfl(pkT, laneL, 64);
  int pR = __shfl(pkB, laneR, 64);
  u64 EW = (E << 8) | (u64)(pL & 255);
  u64 DW = (D << 8) | (u64)((pL >> 8) & 7);
  u64 GW = (Gv << 8) | (u64)((pL >> 11) & 1);
  u64 EE = (E >> 8) | ((u64)(pR & 255) << 56);
  u64 DE = (D >> 8) | ((u64)((pR >> 8) & 7) << 56);
  u64 GE = (Gv >> 8) | ((u64)((pR >> 11) & 1) << 56);
  u64 dbl, dbr;
  if (left) {
    u64 fdE = (fd >> 8) | ((u64)((pR >> 12) & 1) << 56);
    dbl = fd  & eqb(E, el)  & ndB & gtb(D, DW) & GW & Gv;
    dbr = fdE & eqb(EE, el) & ndE & gtb(DE, D) & GE & Gv;
    mom += dbr << 1;
    u64 Ml = mexp(dbl), Mr = mexp(dbr), kp = ~(Ml | Mr);
    E  = (EW & Ml) | (EE & Mr) | (E  & kp);
    D  = (DW & Ml) | (DE & Mr) | (D  & kp);
    Gv = (GW & Ml) | (GE & Mr) | (Gv & kp);
  } else {
    u64 fdW = (fd << 8) | (u64)((pL >> 12) & 1);
    dbl = (fd  ^ ONE8) & eqb(E, el)  & ndB & gtb(D, DE) & GE & Gv;
    dbr = (fdW ^ ONE8) & eqb(EW, el) & ndW & gtb(DW, D) & GW & Gv;
    mom -= dbr << 1;
    u64 Ml = mexp(dbl), Mr = mexp(dbr), kp = ~(Ml | Mr);
    E  = (EE & Ml) | (EW & Mr) | (E  & kp);
    D  = (DE & Ml) | (DW & Mr) | (D  & kp);
    Gv = (GE & Ml) | (GW & Mr) | (Gv & kp);
  }
}

// ============ K2: SWAR chain, inline 3x3, fire2+fluid fused, OUT=2, 4 blocks/CU ============
// u64[rows][64], abs row = ty + idx - off:
//  E0s/RBs 14 off6 | EASs 12 off5 | B1s 10 off4 | HBNs 8 off3 | ELs 6 off2
__global__ __launch_bounds__(512) void k_rest(const unsigned char* __restrict__ e0g,
                                              const unsigned char* __restrict__ rbg,
                                              const float* __restrict__ vin,
                                              float* __restrict__ out) {
  __shared__ u64 E0s[14][64];
  __shared__ u64 RBs[14][64];
  __shared__ u64 EASs[12][64];
  __shared__ u64 B1s[10][64];
  __shared__ u64 HBNs[8][64];
  __shared__ u64 ELs[6][64];
  __shared__ u64 nmsW[2][64];

  int tid = threadIdx.x;
  // T1 XCD swizzle: 1024 blocks, 8 XCDs, 1024%8==0 -> bijective. Groups 128
  // consecutive bands per XCD so halo rows are XCD-L2-resident.
  int blk0 = blockIdx.x;
  int blk = (blk0 & 7) * 128 + (blk0 >> 3);
  int b = blk >> 8;                 // 256 bands per batch
  int ty = (blk & 255) << 1;        // OUT = 2
  int bbase = b * HW;
  float* vout = out + NWORLD;

  // ---- T14 prefetch: vin rows [ty, ty+2) into registers (consumed in hbn phase)
  float vyR[2], vxR[2];
  #pragma unroll
  for (int r = 0; r < 2; ++r) {
    vyR[r] = vin[(size_t)(b*2+0)*HW + ((ty + r) << 9) + tid];
    vxR[r] = vin[(size_t)(b*2+1)*HW + ((ty + r) << 9) + tid];
  }

  // ---- stage e0 + rb rows [ty-6, ty+8): 14 rows x 32 chunks x 16B = 448 threads
  if (tid < 448) {
    int l = tid >> 5, ch = (tid & 31) << 4;
    int gy = (ty + l - 6) & 511;
    int gi = bbase + (gy << 9) + ch;
    *reinterpret_cast<uint4*>(reinterpret_cast<char*>(&E0s[l][0]) + ch) =
        *reinterpret_cast<const uint4*>(e0g + gi);
    *reinterpret_cast<uint4*>(reinterpret_cast<char*>(&RBs[l][0]) + ch) =
        *reinterpret_cast<const uint4*>(rbg + gi);
  }
  __syncthreads();

  int w = tid & 63, rsl = tid >> 6;

  // ---- acid -> EAS[0..11] (abs ty+l-5), vertical roll (wrapped staging)
  #pragma unroll
  for (int l = rsl; l < 12; l += 8) {
    u64 eu = E0s[l][w], ec = E0s[l+1][w], ed = E0s[l+2][w];
    u64 ru = RBs[l][w], rc = RBs[l+1][w], rd = RBs[l+2][w];
    u64 ibu = isblkw(eu), ibc = isblkw(ec), ibd = isblkw(ed);
    u64 da = eqb(ec,E_ACID) & ((rc>>1)&ONE8) & (ibd | ibu);
    u64 db = ibc & ((((ru>>1)&ONE8) & eqb(eu,E_ACID)) | (((rd>>1)&ONE8) & eqb(ed,E_ACID)));
    EASs[l][w] = ec & ~mexp(da | db);
  }
  __syncthreads();

  // ---- fire1 -> B1[0..9] (abs ty+l-4): hfn = inline 3x3 OR of fire|lava(EAS), zero-pad
  #pragma unroll
  for (int l = rsl; l < 10; l += 8) {
    int a = (ty + l - 4) & 511;
    u64 C1 = fl01w(EASs[l+1][w]);
    u64 L1 = w ? fl01w(EASs[l+1][w-1]) : 0;
    u64 R1 = (w < 63) ? fl01w(EASs[l+1][w+1]) : 0;
    u64 hf = C1 | (C1<<8) | (L1>>56) | (C1>>8) | (R1<<56);
    if (a != 0) {
      u64 C0 = fl01w(EASs[l][w]);
      u64 L0 = w ? fl01w(EASs[l][w-1]) : 0;
      u64 R0 = (w < 63) ? fl01w(EASs[l][w+1]) : 0;
      hf |= C0 | (C0<<8) | (L0>>56) | (C0>>8) | (R0<<56);
    }
    if (a != 511) {
      u64 C2 = fl01w(EASs[l+2][w]);
      u64 L2 = w ? fl01w(EASs[l+2][w-1]) : 0;
      u64 R2 = (w < 63) ? fl01w(EASs[l+2][w+1]) : 0;
      hf |= C2 | (C2<<8) | (L2>>56) | (C2>>8) | (R2<<56);
    }
    u64 e = EASs[l+1][w], rb = RBs[l+2][w];
    u64 m0 = rb & ONE8, m1 = (rb>>1) & ONE8;
    u64 eqd = eqb(e,E_DUST);
    u64 dbv = (eqb(e,E_WOOD)&m0) | (eqb(e,E_PLANT)&m1) | (eqb(e,E_GAS)&m1) | eqd;
    u64 burn = dbv & hf;
    u64 ice = eqb(e,E_ICE) & m1 & hf;
    u64 Mb = mexp(burn), Mi = mexp(ice) & ~Mb;
    u64 e1 = (bcast(E_FIRE) & Mb) | (bcast(E_WATER) & Mi) | (e & ~(Mb|Mi));
    B1s[l][w] = e1 | (burn<<4) | ((eqd & hf)<<5);
  }
  __syncthreads();

  // ---- hbn -> HBN[0..7] (abs ty+l-3): inline 3x3 byte-sum of burnable(e1), 1 row/wave
  {
    int l = rsl;
    int a = (ty + l - 3) & 511;
    u64 C1 = burn01w(B1s[l+1][w]);
    u64 L1 = w ? burn01w(B1s[l+1][w-1]) : 0;
    u64 R1 = (w < 63) ? burn01w(B1s[l+1][w+1]) : 0;
    u64 s = C1 + ((C1<<8)|(L1>>56)) + ((C1>>8)|(R1<<56));
    if (a != 0) {
      u64 C0 = burn01w(B1s[l][w]);
      u64 L0 = w ? burn01w(B1s[l][w-1]) : 0;
      u64 R0 = (w < 63) ? burn01w(B1s[l][w+1]) : 0;
      s += C0 + ((C0<<8)|(L0>>56)) + ((C0>>8)|(R0<<56));
    }
    if (a != 511) {
      u64 C2 = burn01w(B1s[l+2][w]);
      u64 L2 = w ? burn01w(B1s[l+2][w-1]) : 0;
      u64 R2 = (w < 63) ? burn01w(B1s[l+2][w+1]) : 0;
      s += C2 + ((C2<<8)|(L2>>56)) + ((C2>>8)|(R2<<56));
    }
    HBNs[l][w] = s;
  }
  // ---- velocity rows [0,2): B1 stable since fire1 barrier; vin already in registers.
  {
    const unsigned char* B1b = reinterpret_cast<const unsigned char*>(&B1s[0][0]);
    int x = tid;
    int xl1 = (x + 511) & 511, xr1 = (x + 1) & 511;
    #pragma unroll
    for (int r = 0; r < 2; ++r) {
      int gy = ty + r;
      int fu  = B1b[(r+3)*512 + x];
      int fd_ = B1b[(r+5)*512 + x];
      int flf = B1b[(r+4)*512 + xl1];
      int frt = B1b[(r+4)*512 + xr1];
      float vy = vyR[r];
      vy = vy + 2.0f*(float)((fu>>4)&1);   vy = vy - 2.0f*(float)((fd_>>4)&1);
      vy = vy + 20.0f*(float)((fu>>5)&1);  vy = vy - 20.0f*(float)((fd_>>5)&1);
      float vx = vxR[r];
      vx = vx + 2.0f*(float)((flf>>4)&1);  vx = vx - 2.0f*(float)((frt>>4)&1);
      vx = vx + 20.0f*(float)((flf>>5)&1); vx = vx - 20.0f*(float)((frt>>5)&1);
      vout[(size_t)(b*2+0)*HW + (gy<<9) + x] = vy;
      vout[(size_t)(b*2+1)*HW + (gy<<9) + x] = vx;
    }
  }
  __syncthreads();

  // ---- fire2 (rows 0..5, abs ty+rsl-2) -> register EF -> SWAR fluid, no barrier between
  if (rsl < 6) {
    int l = rsl;
    int a = (ty + l - 2) & 511;
    #define GW_(g, ww) ((HBNs[g][ww] & mexp(fl01w(EASs[(g)+2][ww]))) + eqb(B1s[(g)+1][ww] & LOWN, E_LAVA))
    u64 C1 = GW_(l+1, w);
    u64 L1 = w ? GW_(l+1, w-1) : 0;
    u64 R1 = (w < 63) ? GW_(l+1, w+1) : 0;
    u64 ifr = C1 + ((C1<<8)|(L1>>56)) + ((C1>>8)|(R1<<56));
    if (a != 0) {
      u64 C0 = GW_(l, w);
      u64 L0 = w ? GW_(l, w-1) : 0;
      u64 R0 = (w < 63) ? GW_(l, w+1) : 0;
      ifr += C0 + ((C0<<8)|(L0>>56)) + ((C0>>8)|(R0<<56));
    }
    if (a != 511) {
      u64 C2 = GW_(l+2, w);
      u64 L2 = w ? GW_(l+2, w-1) : 0;
      u64 R2 = (w < 63) ? GW_(l+2, w+1) : 0;
      ifr += C2 + ((C2<<8)|(L2>>56)) + ((C2>>8)|(R2<<56));
    }
    #undef GW_
    u64 nz = ((ifr + K7F) >> 7) & ONE8;        // byte > 0 (max 90+127 < 256)
    u64 e1 = B1s[l+2][w] & LOWN;
    u64 rbW = RBs[l+4][w];
    u64 dbe = eqb(e1,E_EMPTY) & nz & ((rbW>>2)&ONE8);
    u64 e2 = e1 | (bcast(E_FIRE) & mexp(dbe));
    u64 fe = eqb(e2,E_FIRE) & ((rbW>>3)&ONE8) & eqb(HBNs[l+1][w], 0);
    u64 E = e2 & ~mexp(fe);                    // EF row rsl, in register

    // ---- SWAR fluid on E directly (same wave owns the same row)
    u64 rmB = (rbW >> 4) & ONE8;
    u64 ndB = (rbW >> 5) & ONE8;
    u64 g1 = eqb(E,1), g5 = eqb(E,5), g8 = eqb(E,8), g13 = eqb(E,13);
    u64 m5 = g1|g5|eqb(E,6)|g8|g13;
    u64 m3 = eqb(E,2)|eqb(E,10)|eqb(E,12);
    u64 m2 = eqb(E,3)|eqb(E,11);
    u64 D = ONE8 + ((m5<<2)+m5) + ((m3<<1)+m3) + (m2<<1) + (eqb(E,9)<<2) - eqb(E,4);
    u64 Gv = ONE8 ^ (g1|g5|g8|g13);
    u64 mom = bcast(32);

    int lane = w;
    int laneL = (lane + 63) & 63, laneR = (lane + 1) & 63;
    int ndpk = (int)(ndB >> 56) | (((int)ndB & 1) << 1);
    u64 ndTopL = (u64)(__shfl(ndpk, laneL, 64) & 1);
    u64 ndBotR = (u64)((__shfl(ndpk, laneR, 64) >> 1) & 1);
    u64 ndW = (ndB << 8) | ndTopL;
    u64 ndE = (ndB >> 8) | (ndBotR << 56);

    #pragma unroll
    for (int ei = 0; ei < 5; ++ei) {
      const int el = (ei==0) ? E_EMPTY : (ei==1) ? E_WATER : (ei==2) ? E_GAS
                   : (ei==3) ? E_LAVA  : E_ACID;
      fstep(true,  el, E, D, Gv, mom, rmB, ndB, ndW, ndE, laneL, laneR);
      fstep(false, el, E, D, Gv, mom, rmB, ndB, ndW, ndE, laneL, laneR);
    }
    ELs[rsl][lane] = E;
    if (rsl == 2 || rsl == 3) nmsW[rsl - 2][lane] = mom;   // biased +32
  }
  __syncthreads();

  // ---- cloner + expand: 512 threads; quad q=tid&255 (row r=q>>7, x0=(q&127)*4),
  //      half h=tid>>8 writes channels [9h, 9h+9). Decisions computed redundantly.
  {
    const unsigned char* ELb = reinterpret_cast<const unsigned char*>(&ELs[0][0]);
    const unsigned char* NMb = reinterpret_cast<const unsigned char*>(&nmsW[0][0]);
    int q = tid & 255, h = tid >> 8;
    int r = q >> 7;                 // 0..1
    int x0 = (q & 127) << 2;
    const int DY[4] = {1, -1, 0, 0};
    const int DX[4] = {0, 0, -1, 1};
    int eo[4]; float mom[4], cao[4];
    #pragma unroll
    for (int k = 0; k < 4; ++k) {
      int xx = x0 + k;
      int ry = r + 2;               // EL row of this cell
      int ec = ELb[ry*512 + xx];
      float m = (float)((int)NMb[r*512 + xx] - 32);
      int e = ec; float ca = 0.f;
      if (ec == E_CLONER) {
        int c = ELb[(ry+1)*512 + xx];
        if (c==0||c==13) c = ELb[(ry-1)*512 + xx];
        if (c==0||c==13) c = ELb[ry*512 + ((xx+511)&511)];
        if (c==0||c==13) c = ELb[ry*512 + ((xx+1)&511)];
        ca = (float)c;
      } else if (ec == E_EMPTY) {
        #pragma unroll
        for (int d = 0; d < 4; ++d) {
          int qy = ry + DY[d], qx = (xx + DX[d]) & 511;
          if (ELb[qy*512 + qx] == E_CLONER) {
            int c = ELb[(qy+1)*512 + qx];
            if (c==0||c==13) c = ELb[(qy-1)*512 + qx];
            if (c==0||c==13) c = ELb[qy*512 + ((qx+511)&511)];
            if (c==0||c==13) c = ELb[qy*512 + ((qx+1)&511)];
            if (c != 0 && c != 13) { e = c; m = 0.f; break; }
          }
        }
      }
      eo[k] = e; mom[k] = m; cao[k] = ca;
    }
    float* ob = out + (size_t)b * CH * HW + ((ty + r) << 9) + x0;
    int c0 = h * 9, c1 = c0 + 9;
    for (int c = c0; c < c1; ++c) {
      float4 v;
      if (c < 14) {
        v = make_float4(eo[0]==c ? 1.f : 0.f, eo[1]==c ? 1.f : 0.f,
                        eo[2]==c ? 1.f : 0.f, eo[3]==c ? 1.f : 0.f);
      } else if (c == 14) {
        v = make_float4(c_dens[eo[0]], c_dens[eo[1]], c_dens[eo[2]], c_dens[eo[3]]);
      } else if (c == 15) {
        v = make_float4(c_grav[eo[0]], c_grav[eo[1]], c_grav[eo[2]], c_grav[eo[3]]);
      } else if (c == 16) {
        v = make_float4(mom[0], mom[1], mom[2], mom[3]);
      } else {
        v = make_float4(cao[0], cao[1], cao[2], cao[3]);
      }
      *reinterpret_cast<float4*>(ob + (size_t)c * HW) = v;
    }
  }
}

extern "C" void kernel_launch(void* const* d_in, const int* in_sizes, int n_in,
                              void* d_out, int out_size, void* d_ws, size_t ws_size,
                              hipStream_t stream) {
  const float* world = (const float*)d_in[0];
  const float* rm    = (const float*)d_in[1];
  const float* ri    = (const float*)d_in[2];
  const float* re    = (const float*)d_in[3];
  const float* vel   = (const float*)d_in[4];
  const float* dg    = (const float*)d_in[5];
  float* out = (float*)d_out;

  char* ws = (char*)d_ws;
  unsigned char* e0 = (unsigned char*)ws;
  unsigned char* rb = e0 + NPIX;

  hipLaunchKernelGGL(k_prep, dim3(NPIX/1024), dim3(256), 0, stream,
                     world, ri, re, rm, dg, e0, rb);
  hipLaunchKernelGGL(k_rest, dim3(4*256), dim3(512), 0, stream,
                     e0, rb, vel, out);
}

// Round 13
// 42.435 us; speedup vs baseline: 1.3058x; 1.3058x over previous
//
#include <hip/hip_runtime.h>

// Element ids
#define E_EMPTY  0
#define E_WALL   1
#define E_SAND   2
#define E_WATER  3
#define E_GAS    4
#define E_WOOD   5
#define E_ICE    6
#define E_FIRE   7
#define E_PLANT  8
#define E_STONE  9
#define E_LAVA   10
#define E_ACID   11
#define E_DUST   12
#define E_CLONER 13

#define CH 18
#define HW (512*512)          // 2^18
#define NPIX (4*HW)
#define NWORLD (4*CH*HW)

typedef unsigned long long u64;
typedef float f4 __attribute__((ext_vector_type(4)));   // native vector for NT stores
#define ONE8 0x0101010101010101ULL
#define K7F  0x7F7F7F7F7F7F7F7FULL
#define H80  0x8080808080808080ULL
#define LOWN 0x0F0F0F0F0F0F0F0FULL

__constant__ float c_dens[14] = {0.f,5.f,3.f,2.f,-1.f,5.f,5.f,0.f,5.f,4.f,3.f,2.f,3.f,5.f};
__constant__ float c_grav[14] = {1.f,0.f,1.f,1.f,1.f,0.f,1.f,1.f,0.f,1.f,1.f,1.f,1.f,0.f};

__device__ __forceinline__ u64 bcast(int k) { return ONE8 * (unsigned)k; }
// per-byte equality -> 0x01 bytes (requires bytes <= 0x7F)
__device__ __forceinline__ u64 eqb(u64 x, int k) {
  u64 y = x ^ bcast(k);
  return ((~(y + K7F)) >> 7) & ONE8;
}
// per-byte a >= b -> 0x01 bytes (requires bytes <= 0x7F)
__device__ __forceinline__ u64 geb(u64 a, u64 b) { return (((a | H80) - b) >> 7) & ONE8; }
// per-byte a > b
__device__ __forceinline__ u64 gtb(u64 a, u64 b) { return ONE8 ^ geb(b, a); }
// 0/1-byte mask -> 0x00/0xFF byte mask
__device__ __forceinline__ u64 mexp(u64 m) { return (m << 8) - m; }
__device__ __forceinline__ u64 fl01w(u64 e) { return eqb(e, E_FIRE) | eqb(e, E_LAVA); }
__device__ __forceinline__ u64 burn01w(u64 b) {
  u64 e = b & LOWN;
  return eqb(e,E_WOOD) | eqb(e,E_PLANT) | eqb(e,E_GAS) | eqb(e,E_DUST);
}
__device__ __forceinline__ u64 isblkw(u64 e) {
  return ONE8 ^ (eqb(e,E_EMPTY) | eqb(e,E_WALL) | eqb(e,E_ACID) | eqb(e,E_CLONER));
}

// ---- K1: decode one-hot world (9 planes) -> u8 id; fold all rand thresholds -> bit-pack.
// rb bits: 0: ri<0.05, 1: ri<0.2, 2: ri<0.3, 3: re<0.4, 4: rm>0.5, 5: dg<=0
__device__ __forceinline__ unsigned char decode1(float d, float g, float f, float wa,
                                                 float wo, float pl, float sa, float lv, float wt) {
  if (g < 0.5f) {
    if (wa > 0.5f) return E_WALL;
    if (wo > 0.5f) return E_WOOD;
    if (pl > 0.5f) return E_PLANT;
    return E_CLONER;
  }
  int di = (int)d;          // d in {-1,0,2,3,4,5}, exact
  if (di == 0) return (f > 0.5f) ? E_FIRE : E_EMPTY;
  if (di == 5) return E_ICE;
  if (di == 4) return E_STONE;
  if (di < 0)  return E_GAS;
  if (di == 3) { if (sa > 0.5f) return E_SAND; if (lv > 0.5f) return E_LAVA; return E_DUST; }
  return (wt > 0.5f) ? E_WATER : E_ACID;
}

__global__ __launch_bounds__(256) void k_prep(const float* __restrict__ w,
                                              const float* __restrict__ ri,
                                              const float* __restrict__ re,
                                              const float* __restrict__ rm,
                                              const float* __restrict__ dg,
                                              unsigned char* __restrict__ e0,
                                              unsigned char* __restrict__ rb) {
  int g = blockIdx.x * 256 + threadIdx.x;
  int base = g << 2;
  int b = base >> 18;
  int r = base & (HW - 1);
  const float* wb = w + (size_t)b * CH * HW + r;
  float4 D  = *reinterpret_cast<const float4*>(wb + (size_t)14 * HW);
  float4 G  = *reinterpret_cast<const float4*>(wb + (size_t)15 * HW);
  float4 F  = *reinterpret_cast<const float4*>(wb + (size_t)7  * HW);
  float4 WA = *reinterpret_cast<const float4*>(wb + (size_t)1  * HW);
  float4 WO = *reinterpret_cast<const float4*>(wb + (size_t)5  * HW);
  float4 PL = *reinterpret_cast<const float4*>(wb + (size_t)8  * HW);
  float4 SA = *reinterpret_cast<const float4*>(wb + (size_t)2  * HW);
  float4 LV = *reinterpret_cast<const float4*>(wb + (size_t)10 * HW);
  float4 WT = *reinterpret_cast<const float4*>(wb + (size_t)3  * HW);
  uchar4 e;
  e.x = decode1(D.x, G.x, F.x, WA.x, WO.x, PL.x, SA.x, LV.x, WT.x);
  e.y = decode1(D.y, G.y, F.y, WA.y, WO.y, PL.y, SA.y, LV.y, WT.y);
  e.z = decode1(D.z, G.z, F.z, WA.z, WO.z, PL.z, SA.z, LV.z, WT.z);
  e.w = decode1(D.w, G.w, F.w, WA.w, WO.w, PL.w, SA.w, LV.w, WT.w);
  *reinterpret_cast<uchar4*>(e0 + base) = e;

  float4 RI = *reinterpret_cast<const float4*>(ri + base);
  float4 RE = *reinterpret_cast<const float4*>(re + base);
  float4 RM = *reinterpret_cast<const float4*>(rm + base);
  float4 DG = *reinterpret_cast<const float4*>(dg + base);
  uchar4 q;
  q.x = (RI.x<0.05f?1:0)|(RI.x<0.2f?2:0)|(RI.x<0.3f?4:0)|(RE.x<0.4f?8:0)|(RM.x>0.5f?16:0)|(DG.x<=0.f?32:0);
  q.y = (RI.y<0.05f?1:0)|(RI.y<0.2f?2:0)|(RI.y<0.3f?4:0)|(RE.y<0.4f?8:0)|(RM.y>0.5f?16:0)|(DG.y<=0.f?32:0);
  q.z = (RI.z<0.05f?1:0)|(RI.z<0.2f?2:0)|(RI.z<0.3f?4:0)|(RE.z<0.4f?8:0)|(RM.z>0.5f?16:0)|(DG.z<=0.f?32:0);
  q.w = (RI.w<0.05f?1:0)|(RI.w<0.2f?2:0)|(RI.w<0.3f?4:0)|(RE.w<0.4f?8:0)|(RM.w>0.5f?16:0)|(DG.w<=0.f?32:0);
  *reinterpret_cast<uchar4*>(rb + base) = q;
}

// ---- SWAR fluid substep (verified exact in R8)
__device__ __forceinline__ void fstep(bool left, int el, u64& E, u64& D, u64& Gv, u64& mom,
                                      u64 rmB, u64 ndB, u64 ndW, u64 ndE,
                                      int laneL, int laneR) {
  u64 fd = geb(mom, bcast(33)) | (eqb(mom, 32) & rmB);
  int pkT = (int)(E >> 56) | (((int)(D >> 56)) << 8) | (((int)(Gv >> 56)) << 11)
          | (((int)(fd >> 56)) << 12);
  int pkB = ((int)E & 255) | (((int)D & 255) << 8) | (((int)Gv & 1) << 11)
          | (((int)fd & 1) << 12);
  int pL = __shfl(pkT, laneL, 64);
  int pR = __shfl(pkB, laneR, 64);
  u64 EW = (E << 8) | (u64)(pL & 255);
  u64 DW = (D << 8) | (u64)((pL >> 8) & 7);
  u64 GW = (Gv << 8) | (u64)((pL >> 11) & 1);
  u64 EE = (E >> 8) | ((u64)(pR & 255) << 56);
  u64 DE = (D >> 8) | ((u64)((pR >> 8) & 7) << 56);
  u64 GE = (Gv >> 8) | ((u64)((pR >> 11) & 1) << 56);
  u64 dbl, dbr;
  if (left) {
    u64 fdE = (fd >> 8) | ((u64)((pR >> 12) & 1) << 56);
    dbl = fd  & eqb(E, el)  & ndB & gtb(D, DW) & GW & Gv;
    dbr = fdE & eqb(EE, el) & ndE & gtb(DE, D) & GE & Gv;
    mom += dbr << 1;
    u64 Ml = mexp(dbl), Mr = mexp(dbr), kp = ~(Ml | Mr);
    E  = (EW & Ml) | (EE & Mr) | (E  & kp);
    D  = (DW & Ml) | (DE & Mr) | (D  & kp);
    Gv = (GW & Ml) | (GE & Mr) | (Gv & kp);
  } else {
    u64 fdW = (fd << 8) | (u64)((pL >> 12) & 1);
    dbl = (fd  ^ ONE8) & eqb(E, el)  & ndB & gtb(D, DE) & GE & Gv;
    dbr = (fdW ^ ONE8) & eqb(EW, el) & ndW & gtb(DW, D) & GW & Gv;
    mom -= dbr << 1;
    u64 Ml = mexp(dbl), Mr = mexp(dbr), kp = ~(Ml | Mr);
    E  = (EE & Ml) | (EW & Mr) | (E  & kp);
    D  = (DE & Ml) | (DW & Mr) | (D  & kp);
    Gv = (GE & Ml) | (GW & Mr) | (Gv & kp);
  }
}

// ============ K2: SWAR chain, inline 3x3, fire2+fluid fused in-register, 5 barriers ============
// OUT=4, 512 blocks, XCD-swizzled; NT stores for vel + output.
// u64[rows][64], abs row = ty + idx - off:
//  E0s/RBs 16 off6 | EASs 14 off5 | B1s 12 off4 | HBNs 10 off3 | ELs 8 off2
__global__ __launch_bounds__(512) void k_rest(const unsigned char* __restrict__ e0g,
                                              const unsigned char* __restrict__ rbg,
                                              const float* __restrict__ vin,
                                              float* __restrict__ out) {
  __shared__ u64 E0s[16][64];
  __shared__ u64 RBs[16][64];
  __shared__ u64 EASs[14][64];
  __shared__ u64 B1s[12][64];
  __shared__ u64 HBNs[10][64];
  __shared__ u64 ELs[8][64];
  __shared__ u64 nmsW[4][64];

  int tid = threadIdx.x;
  // T1 bijective XCD swizzle (512 blocks % 8 == 0): 64 consecutive bands per XCD
  // so band-halo rows of neighbors are XCD-L2-resident.
  int blk0 = blockIdx.x;
  int blk = (blk0 & 7) * 64 + (blk0 >> 3);
  int b = blk >> 7;                 // 128 bands per batch
  int ty = (blk & 127) << 2;        // OUT = 4
  int bbase = b * HW;
  float* vout = out + NWORLD;

  // ---- T14 prefetch: vin rows [ty, ty+4) into registers (consumed in hbn phase)
  float vyR[4], vxR[4];
  #pragma unroll
  for (int r = 0; r < 4; ++r) {
    vyR[r] = vin[(size_t)(b*2+0)*HW + ((ty + r) << 9) + tid];
    vxR[r] = vin[(size_t)(b*2+1)*HW + ((ty + r) << 9) + tid];
  }

  // ---- stage e0 + rb rows [ty-6, ty+10): 16 rows x 32 chunks x 16B
  {
    int l = tid >> 5, ch = (tid & 31) << 4;
    int gy = (ty + l - 6) & 511;
    int gi = bbase + (gy << 9) + ch;
    *reinterpret_cast<uint4*>(reinterpret_cast<char*>(&E0s[l][0]) + ch) =
        *reinterpret_cast<const uint4*>(e0g + gi);
    *reinterpret_cast<uint4*>(reinterpret_cast<char*>(&RBs[l][0]) + ch) =
        *reinterpret_cast<const uint4*>(rbg + gi);
  }
  __syncthreads();

  int w = tid & 63, rsl = tid >> 6;

  // ---- acid -> EAS[0..13] (abs ty+l-5), vertical roll (wrapped staging)
  #pragma unroll
  for (int l = rsl; l < 14; l += 8) {
    u64 eu = E0s[l][w], ec = E0s[l+1][w], ed = E0s[l+2][w];
    u64 ru = RBs[l][w], rc = RBs[l+1][w], rd = RBs[l+2][w];
    u64 ibu = isblkw(eu), ibc = isblkw(ec), ibd = isblkw(ed);
    u64 da = eqb(ec,E_ACID) & ((rc>>1)&ONE8) & (ibd | ibu);
    u64 db = ibc & ((((ru>>1)&ONE8) & eqb(eu,E_ACID)) | (((rd>>1)&ONE8) & eqb(ed,E_ACID)));
    EASs[l][w] = ec & ~mexp(da | db);
  }
  __syncthreads();

  // ---- fire1 -> B1[0..11] (abs ty+l-4): hfn = inline 3x3 OR of fire|lava(EAS), zero-pad
  #pragma unroll
  for (int l = rsl; l < 12; l += 8) {
    int a = (ty + l - 4) & 511;
    u64 C1 = fl01w(EASs[l+1][w]);
    u64 L1 = w ? fl01w(EASs[l+1][w-1]) : 0;
    u64 R1 = (w < 63) ? fl01w(EASs[l+1][w+1]) : 0;
    u64 hf = C1 | (C1<<8) | (L1>>56) | (C1>>8) | (R1<<56);
    if (a != 0) {
      u64 C0 = fl01w(EASs[l][w]);
      u64 L0 = w ? fl01w(EASs[l][w-1]) : 0;
      u64 R0 = (w < 63) ? fl01w(EASs[l][w+1]) : 0;
      hf |= C0 | (C0<<8) | (L0>>56) | (C0>>8) | (R0<<56);
    }
    if (a != 511) {
      u64 C2 = fl01w(EASs[l+2][w]);
      u64 L2 = w ? fl01w(EASs[l+2][w-1]) : 0;
      u64 R2 = (w < 63) ? fl01w(EASs[l+2][w+1]) : 0;
      hf |= C2 | (C2<<8) | (L2>>56) | (C2>>8) | (R2<<56);
    }
    u64 e = EASs[l+1][w], rb = RBs[l+2][w];
    u64 m0 = rb & ONE8, m1 = (rb>>1) & ONE8;
    u64 eqd = eqb(e,E_DUST);
    u64 dbv = (eqb(e,E_WOOD)&m0) | (eqb(e,E_PLANT)&m1) | (eqb(e,E_GAS)&m1) | eqd;
    u64 burn = dbv & hf;
    u64 ice = eqb(e,E_ICE) & m1 & hf;
    u64 Mb = mexp(burn), Mi = mexp(ice) & ~Mb;
    u64 e1 = (bcast(E_FIRE) & Mb) | (bcast(E_WATER) & Mi) | (e & ~(Mb|Mi));
    B1s[l][w] = e1 | (burn<<4) | ((eqd & hf)<<5);
  }
  __syncthreads();

  // ---- hbn -> HBN[0..9] (abs ty+l-3): inline 3x3 byte-sum of burnable(e1)
  #pragma unroll
  for (int l = rsl; l < 10; l += 8) {
    int a = (ty + l - 3) & 511;
    u64 C1 = burn01w(B1s[l+1][w]);
    u64 L1 = w ? burn01w(B1s[l+1][w-1]) : 0;
    u64 R1 = (w < 63) ? burn01w(B1s[l+1][w+1]) : 0;
    u64 s = C1 + ((C1<<8)|(L1>>56)) + ((C1>>8)|(R1<<56));
    if (a != 0) {
      u64 C0 = burn01w(B1s[l][w]);
      u64 L0 = w ? burn01w(B1s[l][w-1]) : 0;
      u64 R0 = (w < 63) ? burn01w(B1s[l][w+1]) : 0;
      s += C0 + ((C0<<8)|(L0>>56)) + ((C0>>8)|(R0<<56));
    }
    if (a != 511) {
      u64 C2 = burn01w(B1s[l+2][w]);
      u64 L2 = w ? burn01w(B1s[l+2][w-1]) : 0;
      u64 R2 = (w < 63) ? burn01w(B1s[l+2][w+1]) : 0;
      s += C2 + ((C2<<8)|(L2>>56)) + ((C2>>8)|(R2<<56));
    }
    HBNs[l][w] = s;
  }
  // ---- velocity rows [0,4): B1 stable since fire1 barrier; vin already in registers.
  {
    const unsigned char* B1b = reinterpret_cast<const unsigned char*>(&B1s[0][0]);
    int x = tid;
    int xl1 = (x + 511) & 511, xr1 = (x + 1) & 511;
    #pragma unroll
    for (int r = 0; r < 4; ++r) {
      int gy = ty + r;
      int fu  = B1b[(r+3)*512 + x];
      int fd_ = B1b[(r+5)*512 + x];
      int flf = B1b[(r+4)*512 + xl1];
      int frt = B1b[(r+4)*512 + xr1];
      float vy = vyR[r];
      vy = vy + 2.0f*(float)((fu>>4)&1);   vy = vy - 2.0f*(float)((fd_>>4)&1);
      vy = vy + 20.0f*(float)((fu>>5)&1);  vy = vy - 20.0f*(float)((fd_>>5)&1);
      float vx = vxR[r];
      vx = vx + 2.0f*(float)((flf>>4)&1);  vx = vx - 2.0f*(float)((frt>>4)&1);
      vx = vx + 20.0f*(float)((flf>>5)&1); vx = vx - 20.0f*(float)((frt>>5)&1);
      __builtin_nontemporal_store(vy, vout + (size_t)(b*2+0)*HW + (gy<<9) + x);
      __builtin_nontemporal_store(vx, vout + (size_t)(b*2+1)*HW + (gy<<9) + x);
    }
  }
  __syncthreads();

  // ---- fire2 (row rsl, abs ty+rsl-2) -> register EF -> SWAR fluid, NO barrier/LDS between
  {
    int l = rsl;
    int a = (ty + l - 2) & 511;
    #define GW_(g, ww) ((HBNs[g][ww] & mexp(fl01w(EASs[(g)+2][ww]))) + eqb(B1s[(g)+1][ww] & LOWN, E_LAVA))
    u64 C1 = GW_(l+1, w);
    u64 L1 = w ? GW_(l+1, w-1) : 0;
    u64 R1 = (w < 63) ? GW_(l+1, w+1) : 0;
    u64 ifr = C1 + ((C1<<8)|(L1>>56)) + ((C1>>8)|(R1<<56));
    if (a != 0) {
      u64 C0 = GW_(l, w);
      u64 L0 = w ? GW_(l, w-1) : 0;
      u64 R0 = (w < 63) ? GW_(l, w+1) : 0;
      ifr += C0 + ((C0<<8)|(L0>>56)) + ((C0>>8)|(R0<<56));
    }
    if (a != 511) {
      u64 C2 = GW_(l+2, w);
      u64 L2 = w ? GW_(l+2, w-1) : 0;
      u64 R2 = (w < 63) ? GW_(l+2, w+1) : 0;
      ifr += C2 + ((C2<<8)|(L2>>56)) + ((C2>>8)|(R2<<56));
    }
    #undef GW_
    u64 nz = ((ifr + K7F) >> 7) & ONE8;        // byte > 0 (max 90+127 < 256)
    u64 e1 = B1s[l+2][w] & LOWN;
    u64 rbW = RBs[l+4][w];
    u64 dbe = eqb(e1,E_EMPTY) & nz & ((rbW>>2)&ONE8);
    u64 e2 = e1 | (bcast(E_FIRE) & mexp(dbe));
    u64 fe = eqb(e2,E_FIRE) & ((rbW>>3)&ONE8) & eqb(HBNs[l+1][w], 0);
    u64 E = e2 & ~mexp(fe);                    // EF row rsl, in register

    // ---- SWAR fluid on E directly (same wave owns the same row)
    u64 rmB = (rbW >> 4) & ONE8;
    u64 ndB = (rbW >> 5) & ONE8;
    u64 g1 = eqb(E,1), g5 = eqb(E,5), g8 = eqb(E,8), g13 = eqb(E,13);
    u64 m5 = g1|g5|eqb(E,6)|g8|g13;
    u64 m3 = eqb(E,2)|eqb(E,10)|eqb(E,12);
    u64 m2 = eqb(E,3)|eqb(E,11);
    u64 D = ONE8 + ((m5<<2)+m5) + ((m3<<1)+m3) + (m2<<1) + (eqb(E,9)<<2) - eqb(E,4);
    u64 Gv = ONE8 ^ (g1|g5|g8|g13);
    u64 mom = bcast(32);

    int lane = w;
    int laneL = (lane + 63) & 63, laneR = (lane + 1) & 63;
    int ndpk = (int)(ndB >> 56) | (((int)ndB & 1) << 1);
    u64 ndTopL = (u64)(__shfl(ndpk, laneL, 64) & 1);
    u64 ndBotR = (u64)((__shfl(ndpk, laneR, 64) >> 1) & 1);
    u64 ndW = (ndB << 8) | ndTopL;
    u64 ndE = (ndB >> 8) | (ndBotR << 56);

    #pragma unroll
    for (int ei = 0; ei < 5; ++ei) {
      const int el = (ei==0) ? E_EMPTY : (ei==1) ? E_WATER : (ei==2) ? E_GAS
                   : (ei==3) ? E_LAVA  : E_ACID;
      fstep(true,  el, E, D, Gv, mom, rmB, ndB, ndW, ndE, laneL, laneR);
      fstep(false, el, E, D, Gv, mom, rmB, ndB, ndW, ndE, laneL, laneR);
    }
    ELs[rsl][lane] = E;
    if (rsl >= 2 && rsl < 6) nmsW[rsl - 2][lane] = mom;   // biased +32
  }
  __syncthreads();

  // ---- cloner + expand: 512 threads, quad (row r=tid>>7, x0=(tid&127)*4), 18 NT f4 stores
  {
    const unsigned char* ELb = reinterpret_cast<const unsigned char*>(&ELs[0][0]);
    const unsigned char* NMb = reinterpret_cast<const unsigned char*>(&nmsW[0][0]);
    int r = tid >> 7;               // 0..3
    int x0 = (tid & 127) << 2;
    const int DY[4] = {1, -1, 0, 0};
    const int DX[4] = {0, 0, -1, 1};
    int eo[4]; float mom[4], cao[4];
    #pragma unroll
    for (int k = 0; k < 4; ++k) {
      int xx = x0 + k;
      int ry = r + 2;               // EL row of this cell
      int ec = ELb[ry*512 + xx];
      float m = (float)((int)NMb[r*512 + xx] - 32);
      int e = ec; float ca = 0.f;
      if (ec == E_CLONER) {
        int c = ELb[(ry+1)*512 + xx];
        if (c==0||c==13) c = ELb[(ry-1)*512 + xx];
        if (c==0||c==13) c = ELb[ry*512 + ((xx+511)&511)];
        if (c==0||c==13) c = ELb[ry*512 + ((xx+1)&511)];
        ca = (float)c;
      } else if (ec == E_EMPTY) {
        #pragma unroll
        for (int d = 0; d < 4; ++d) {
          int qy = ry + DY[d], qx = (xx + DX[d]) & 511;
          if (ELb[qy*512 + qx] == E_CLONER) {
            int c = ELb[(qy+1)*512 + qx];
            if (c==0||c==13) c = ELb[(qy-1)*512 + qx];
            if (c==0||c==13) c = ELb[qy*512 + ((qx+511)&511)];
            if (c==0||c==13) c = ELb[qy*512 + ((qx+1)&511)];
            if (c != 0 && c != 13) { e = c; m = 0.f; break; }
          }
        }
      }
      eo[k] = e; mom[k] = m; cao[k] = ca;
    }
    float* ob = out + (size_t)b * CH * HW + ((ty + r) << 9) + x0;
    #pragma unroll
    for (int c = 0; c < 14; ++c) {
      f4 v = {eo[0]==c ? 1.f : 0.f, eo[1]==c ? 1.f : 0.f,
              eo[2]==c ? 1.f : 0.f, eo[3]==c ? 1.f : 0.f};
      __builtin_nontemporal_store(v, reinterpret_cast<f4*>(ob + (size_t)c * HW));
    }
    f4 vd = {c_dens[eo[0]], c_dens[eo[1]], c_dens[eo[2]], c_dens[eo[3]]};
    __builtin_nontemporal_store(vd, reinterpret_cast<f4*>(ob + (size_t)14*HW));
    f4 vg = {c_grav[eo[0]], c_grav[eo[1]], c_grav[eo[2]], c_grav[eo[3]]};
    __builtin_nontemporal_store(vg, reinterpret_cast<f4*>(ob + (size_t)15*HW));
    f4 vm = {mom[0], mom[1], mom[2], mom[3]};
    __builtin_nontemporal_store(vm, reinterpret_cast<f4*>(ob + (size_t)16*HW));
    f4 vc = {cao[0], cao[1], cao[2], cao[3]};
    __builtin_nontemporal_store(vc, reinterpret_cast<f4*>(ob + (size_t)17*HW));
  }
}

extern "C" void kernel_launch(void* const* d_in, const int* in_sizes, int n_in,
                              void* d_out, int out_size, void* d_ws, size_t ws_size,
                              hipStream_t stream) {
  const float* world = (const float*)d_in[0];
  const float* rm    = (const float*)d_in[1];
  const float* ri    = (const float*)d_in[2];
  const float* re    = (const float*)d_in[3];
  const float* vel   = (const float*)d_in[4];
  const float* dg    = (const float*)d_in[5];
  float* out = (float*)d_out;

  char* ws = (char*)d_ws;
  unsigned char* e0 = (unsigned char*)ws;
  unsigned char* rb = e0 + NPIX;

  hipLaunchKernelGGL(k_prep, dim3(NPIX/1024), dim3(256), 0, stream,
                     world, ri, re, rm, dg, e0, rb);
  hipLaunchKernelGGL(k_rest, dim3(4*128), dim3(512), 0, stream,
                     e0, rb, vel, out);
}